// Round 5
// baseline (38.537 us; speedup 1.0000x reference)
//
#include <hip/hip_runtime.h>
#include <math.h>

#define B_TOTAL 16384
#define NQ 512
#define NUM 3

// 16 lanes per batch, 4 batches per wave, 16 batches per 256-thread block.
// Lane t of a group owns 32 conf elements {j*64 + t*4 + c} (slot s = j*4+c),
// loaded as monotone u32 keys via group-contiguous 256B float4 bursts.
// Winner selection is the R3-proven pattern: local value+index argmax tree,
// then packed-u64 (key<<32 | 511-n) butterfly max over the 16-lane group
// (stable smaller-index tie-break), then consume (key -> 0).
__global__ __launch_bounds__(256) void greedy_nms_kernel(
    const float* __restrict__ conf,   // [B, NQ]
    const float* __restrict__ pos,    // [B, NQ, 3]
    float* __restrict__ out)          // [B, NUM, 3]
{
    const int gid = threadIdx.x >> 4;          // group in block: 0..15
    const int t   = threadIdx.x & 15;          // sublane in group
    const int b   = (blockIdx.x << 4) + gid;   // batch for this group

    const float* cb = conf + (size_t)b * NQ;
    const float* pb = pos  + (size_t)b * NQ * 3;

    // slot s = j*4+c  <->  element n = j*64 + t*4 + c
    unsigned k[32];
    const float4* cb4 = reinterpret_cast<const float4*>(cb);
    #pragma unroll
    for (int j = 0; j < 8; ++j) {
        float4 u = cb4[j * 16 + t];            // group reads 256B contiguous
        float f[4] = {u.x, u.y, u.z, u.w};
        #pragma unroll
        for (int c = 0; c < 4; ++c) {
            int bi = __float_as_int(f[c]);
            k[j * 4 + c] = (unsigned)bi ^ ((unsigned)(bi >> 31) | 0x80000000u);
        }
    }

    // exact greedy winner (R3-proven structure): returns element index,
    // consumes it (key -> 0; 0 is below every real key: inputs have no NaN).
    auto next_winner = [&]() -> int {
        unsigned mv[16]; int ms[16];
        #pragma unroll
        for (int i = 0; i < 16; ++i) {
            bool sel = k[2 * i + 1] > k[2 * i];     // tie -> smaller slot
            mv[i] = sel ? k[2 * i + 1] : k[2 * i];
            ms[i] = sel ? (2 * i + 1) : (2 * i);
        }
        #pragma unroll
        for (int st = 8; st >= 1; st >>= 1) {
            #pragma unroll
            for (int i = 0; i < st; ++i)
                if (mv[i + st] > mv[i]) {           // tie keeps smaller slot
                    mv[i] = mv[i + st]; ms[i] = ms[i + st];
                }
        }
        // slot -> element index for this lane (monotone in s for fixed t)
        const int nl = ((ms[0] >> 2) << 6) | (t << 2) | (ms[0] & 3);
        // pack: hi32 = key, lo32 = 511-n (tie -> larger lo -> smaller n)
        unsigned long long key =
            ((unsigned long long)mv[0] << 32) | (unsigned)(NQ - 1 - nl);
        #pragma unroll
        for (int off = 1; off <= 8; off <<= 1) {
            unsigned long long o = __shfl_xor(key, off);
            if (o > key) key = o;
        }
        const int n = NQ - 1 - (int)(unsigned)key;  // low 32 bits hold 511-n
        // consume (compile-time slot indices only)
        const int owner = (n >> 2) & 15;
        const int slx = (owner == t) ? (((n >> 6) << 2) | (n & 3)) : 64;
        #pragma unroll
        for (int s = 0; s < 32; ++s)
            if (slx == s) k[s] = 0u;
        return n;
    };

    const float TH  = 0.78539816339744830961f; // pi/4 (f32 == jnp thresh)
    const float CLO = 0.70710478f;             // cos(pi/4) - ~2e-6
    const float CHI = 0.70710878f;             // cos(pi/4) + ~2e-6

    // accepted set; zero vectors auto-pass (dot 0 <= CLO), mirroring the
    // reference's `where(ar < count, ang, inf)` masking.
    float a0x = 0.f, a0y = 0.f, a0z = 0.f;
    float a1x = 0.f, a1y = 0.f, a1z = 0.f;
    float a2x = 0.f, a2y = 0.f, a2z = 0.f;
    int count = 0;

    #pragma unroll 1
    for (int it = 0; it < NQ; ++it) {
        const int n = next_winner();
        const float px = pb[n * 3 + 0];
        const float py = pb[n * 3 + 1];
        const float pz = pb[n * 3 + 2];

        const float d0 = fabsf(a0x * px + a0y * py + a0z * pz);
        const float d1 = fabsf(a1x * px + a1y * py + a1z * pz);
        const float d2 = fabsf(a2x * px + a2y * py + a2z * pz);
        const float dm = fmaxf(d0, fmaxf(d1, d2));

        bool add;
        if (dm <= CLO) {
            add = true;                          // all angles clearly >= pi/4
        } else if (dm >= CHI) {
            add = false;                         // some angle clearly < pi/4
        } else {                                 // borderline: exact formula
            add = (acosf(fminf(d0, 1.f)) >= TH) &&
                  (acosf(fminf(d1, 1.f)) >= TH) &&
                  (acosf(fminf(d2, 1.f)) >= TH);
        }

        if (add && count < NUM) {
            if (count == 0)      { a0x = px; a0y = py; a0z = pz; }
            else if (count == 1) { a1x = px; a1y = py; a1z = pz; }
            else                 { a2x = px; a2y = py; a2z = pz; }
            ++count;
        }
        if (__all(count >= NUM)) break;          // wave-uniform exit
    }

    // unfilled slots -> pos[0] of this batch (reference cand stayed index 0)
    if (count < NUM) {
        float p0x = pb[0], p0y = pb[1], p0z = pb[2];
        if (count == 0) { a0x = p0x; a0y = p0y; a0z = p0z; }
        if (count <= 1) { a1x = p0x; a1y = p0y; a1z = p0z; }
        a2x = p0x; a2y = p0y; a2z = p0z;
    }

    if (t == 0) {
        float* ob = out + (size_t)b * 9;
        ob[0] = a0x; ob[1] = a0y; ob[2] = a0z;
        ob[3] = a1x; ob[4] = a1y; ob[5] = a1z;
        ob[6] = a2x; ob[7] = a2y; ob[8] = a2z;
    }
}

extern "C" void kernel_launch(void* const* d_in, const int* in_sizes, int n_in,
                              void* d_out, int out_size, void* d_ws, size_t ws_size,
                              hipStream_t stream) {
    const float* pred_logits = (const float*)d_in[0]; // [B, NQ, 1]
    const float* pred_pos    = (const float*)d_in[1]; // [B, NQ, 3]
    float* out = (float*)d_out;                       // [B, NUM, 3]

    const int grid = B_TOTAL / 16;                    // 16 batches per block
    greedy_nms_kernel<<<grid, 256, 0, stream>>>(pred_logits, pred_pos, out);
}

// Round 6
// 26.644 us; speedup vs baseline: 1.4464x; 1.4464x over previous
//
#include <hip/hip_runtime.h>
#include <math.h>

#define B_TOTAL 16384
#define NQ 512
#define NUM 3

// One wave per batch. NUM=3 greedy NMS == three masked argmaxes:
//   #1 = argmax conf
//   #2 = argmax conf among items passing the angle test vs p1
//        (any higher-conf passing item would itself have been #2)
//   #3 = argmax conf among items passing vs p1 AND p2
// Lane l holds conf[8l..8l+7] as monotone u32 keys and pos rows 8l..8l+7
// in registers (streamed once, coalesced). No iteration loop, no scattered
// dependent loads. Tie-break = smallest index, exact via ballot+ffs (lane
// order == index-block order, slot order == index order within a lane).
__global__ __launch_bounds__(256) void greedy_nms_kernel(
    const float* __restrict__ conf,   // [B, NQ]
    const float* __restrict__ pos,    // [B, NQ, 3]
    float* __restrict__ out)          // [B, NUM, 3]
{
    const int wave = threadIdx.x >> 6;
    const int lane = threadIdx.x & 63;
    const int b = (blockIdx.x << 2) + wave;   // grid*4 == B_TOTAL

    const float* cb = conf + (size_t)b * NQ;
    const float* pb = pos  + (size_t)b * NQ * 3;

    // ---- issue all global loads up front (independent, coalesced) ----
    const float4* cb4 = reinterpret_cast<const float4*>(cb);
    float4 c0 = cb4[lane * 2 + 0];
    float4 c1 = cb4[lane * 2 + 1];
    const float4* pb4 = reinterpret_cast<const float4*>(pb);
    float4 q0 = pb4[lane * 6 + 0];
    float4 q1 = pb4[lane * 6 + 1];
    float4 q2 = pb4[lane * 6 + 2];
    float4 q3 = pb4[lane * 6 + 3];
    float4 q4 = pb4[lane * 6 + 4];
    float4 q5 = pb4[lane * 6 + 5];

    // monotone float->u32 keys (no NaNs in input); key 0 == "consumed"
    unsigned k[8];
    {
        float f[8] = {c0.x, c0.y, c0.z, c0.w, c1.x, c1.y, c1.z, c1.w};
        #pragma unroll
        for (int s = 0; s < 8; ++s) {
            int bi = __float_as_int(f[s]);
            k[s] = (unsigned)bi ^ ((unsigned)(bi >> 31) | 0x80000000u);
        }
    }

    // unpack 8 pos rows (row j of this lane = element 8*lane + j)
    float rx[8], ry[8], rz[8];
    {
        float fl[24] = {q0.x, q0.y, q0.z, q0.w, q1.x, q1.y, q1.z, q1.w,
                        q2.x, q2.y, q2.z, q2.w, q3.x, q3.y, q3.z, q3.w,
                        q4.x, q4.y, q4.z, q4.w, q5.x, q5.y, q5.z, q5.w};
        #pragma unroll
        for (int j = 0; j < 8; ++j) {
            rx[j] = fl[3 * j + 0];
            ry[j] = fl[3 * j + 1];
            rz[j] = fl[3 * j + 2];
        }
    }

    // exact argmax over current keys: returns element index + max key.
    // min-index tie-break: first lane (ballot+ffs) then first slot.
    auto argmax_idx = [&](unsigned& gm_out) -> int {
        unsigned m = k[0];
        #pragma unroll
        for (int s = 1; s < 8; ++s) m = k[s] > m ? k[s] : m;
        unsigned gm = m;
        #pragma unroll
        for (int off = 1; off < 64; off <<= 1) {
            unsigned o = __shfl_xor(gm, off);
            gm = o > gm ? o : gm;
        }
        int sl = 8;                        // first local slot equal to max
        #pragma unroll
        for (int s = 7; s >= 0; --s)
            if (k[s] == gm) sl = s;
        unsigned long long ball = __ballot(sl < 8);
        int owner = __ffsll(ball) - 1;
        int osl = __shfl(sl, owner);
        gm_out = gm;
        return owner * 8 + osl;
    };

    // broadcast row w's xyz to all lanes (w wave-uniform)
    auto get_row = [&](int w, float& x, float& y, float& z) {
        const int ow = w >> 3, sl = w & 7;
        float tx = rx[0], ty = ry[0], tz = rz[0];
        #pragma unroll
        for (int s = 1; s < 8; ++s)
            if (sl == s) { tx = rx[s]; ty = ry[s]; tz = rz[s]; }
        x = __shfl(tx, ow); y = __shfl(ty, ow); z = __shfl(tz, ow);
    };

    const float TH  = 0.78539816339744830961f; // pi/4 (f32 == jnp thresh)
    const float CLO = 0.70710478f;             // cos(pi/4) - ~2e-6
    const float CHI = 0.70710878f;             // cos(pi/4) + ~2e-6

    // zero keys of items failing the angle test vs (px,py,pz)
    auto mask_keys = [&](float px, float py, float pz) {
        #pragma unroll
        for (int s = 0; s < 8; ++s) {
            float d = fabsf(rx[s] * px + ry[s] * py + rz[s] * pz);
            bool pass;
            if (d <= CLO)      pass = true;   // clearly >= pi/4
            else if (d >= CHI) pass = false;  // clearly <  pi/4
            else               pass = (acosf(fminf(d, 1.f)) >= TH); // exact
            if (!pass) k[s] = 0u;
        }
    };

    // ---- #1: global argmax ----
    unsigned gm1;
    int w1 = argmax_idx(gm1);
    float p1x, p1y, p1z;
    get_row(w1, p1x, p1y, p1z);
    {   // consume w1
        const int osl = ((w1 >> 3) == lane) ? (w1 & 7) : 8;
        #pragma unroll
        for (int s = 0; s < 8; ++s)
            if (osl == s) k[s] = 0u;
    }

    // fallback vector = pos[0] (reference cand slots stay index 0)
    float p0x, p0y, p0z;
    get_row(0, p0x, p0y, p0z);

    // ---- #2: argmax among items passing vs p1 ----
    mask_keys(p1x, p1y, p1z);
    unsigned gm2;
    int w2 = argmax_idx(gm2);

    float o2x = p0x, o2y = p0y, o2z = p0z;
    float o3x = p0x, o3y = p0y, o3z = p0z;

    if (gm2 != 0u) {                      // wave-uniform
        float p2x, p2y, p2z;
        get_row(w2, p2x, p2y, p2z);
        o2x = p2x; o2y = p2y; o2z = p2z;

        // ---- #3: additionally pass vs p2 (w2 self-fails: |dot|=1) ----
        mask_keys(p2x, p2y, p2z);
        unsigned gm3;
        int w3 = argmax_idx(gm3);
        if (gm3 != 0u) {
            get_row(w3, o3x, o3y, o3z);
        }
    }

    if (lane == 0) {
        float* ob = out + (size_t)b * 9;
        ob[0] = p1x; ob[1] = p1y; ob[2] = p1z;
        ob[3] = o2x; ob[4] = o2y; ob[5] = o2z;
        ob[6] = o3x; ob[7] = o3y; ob[8] = o3z;
    }
}

extern "C" void kernel_launch(void* const* d_in, const int* in_sizes, int n_in,
                              void* d_out, int out_size, void* d_ws, size_t ws_size,
                              hipStream_t stream) {
    const float* pred_logits = (const float*)d_in[0]; // [B, NQ, 1]
    const float* pred_pos    = (const float*)d_in[1]; // [B, NQ, 3]
    float* out = (float*)d_out;                       // [B, NUM, 3]

    const int grid = B_TOTAL / 4;                     // 4 waves/block
    greedy_nms_kernel<<<grid, 256, 0, stream>>>(pred_logits, pred_pos, out);
}